// Round 4
// baseline (1659.569 us; speedup 1.0000x reference)
//
#include <hip/hip_runtime.h>
#include <math.h>

#define NROWS 16384
#define FCN 96
#define T 512
#define NRI 1024
#define LAYERS 16

typedef _Float16 f16;
typedef _Float16 half8 __attribute__((ext_vector_type(8)));
typedef float floatx4 __attribute__((ext_vector_type(4)));

// ws float offsets
#define OFF_PMAX 0                       // 256
#define OFF_SCALE 256                    // [0]=5/max, [1]=max/5
#define OFF_SUMS 512                     // LAYERS*1024 per-n |R|^2 sums
#define OFF_W1H (OFF_SUMS + LAYERS*NRI)  // 98304 f16 = 49152 floats, frag-chunk-linear
#define OFF_W2H (OFF_W1H + 49152)        // 98304 f16
#define OFF_R   (OFF_W2H + 49152)        // 16384*1024 fp32 [b][n]

__global__ void kmax(const float* __restrict__ u, float* __restrict__ pmax, int n) {
    __shared__ float sm[256];
    float m = -1e30f;
    for (int i = blockIdx.x * blockDim.x + threadIdx.x; i < n; i += gridDim.x * blockDim.x)
        m = fmaxf(m, u[i]);
    sm[threadIdx.x] = m;
    __syncthreads();
    for (int s = 128; s > 0; s >>= 1) {
        if (threadIdx.x < s) sm[threadIdx.x] = fmaxf(sm[threadIdx.x], sm[threadIdx.x + s]);
        __syncthreads();
    }
    if (threadIdx.x == 0) pmax[blockIdx.x] = sm[0];
}

__global__ void kinit(float* __restrict__ ws) {
    __shared__ float sm[256];
    int t = threadIdx.x;
    sm[t] = ws[OFF_PMAX + t];
    __syncthreads();
    for (int s = 128; s > 0; s >>= 1) {
        if (t < s) sm[t] = fmaxf(sm[t], sm[t + s]);
        __syncthreads();
    }
    if (t == 0) {
        float m = fabsf(sm[0]);
        ws[OFF_SCALE]     = 5.0f / m;
        ws[OFF_SCALE + 1] = m / 5.0f;
    }
    for (int i = t; i < LAYERS * NRI; i += 256) ws[OFF_SUMS + i] = 0.0f;
}

// Weight tables, f16 single, fragment-chunk-linear layouts.
// W1 [96 k][1024 n]: chunk-linear: idx = (((c*8+nt8)*3+kc)*64+lane)*8+j,
//   k=kc*32+(lane>>4)*8+j, n=c*128+nt8*16+(lane&15).
// W2 [1024 k][96 fc]: idx = (((ch*4+kc)*6+nt)*64+lane)*8+j,
//   k=ch*128+kc*32+(lane>>4)*8+j, fc=nt*16+(lane&15).
__global__ void kwf(float* __restrict__ ws) {
    int idx = blockIdx.x * 256 + threadIdx.x;
    if (idx >= 2 * 98304) return;
    int which = idx >= 98304;
    int id = which ? idx - 98304 : idx;
    int j = id & 7, lane = (id >> 3) & 63, r = id >> 9;
    int k, n, t, f, q, e;
    if (!which) {
        int kc = r % 3, r2 = r / 3, nt8 = r2 & 7, c = r2 >> 3;
        k = kc * 32 + (lane >> 4) * 8 + j;
        n = c * 128 + nt8 * 16 + (lane & 15);
        f = k >> 1; q = k & 1; t = n >> 1; e = n & 1;
    } else {
        int nt = r % 6, r2 = r / 6, kc = r2 & 3, ch = r2 >> 2;
        k = ch * 128 + kc * 32 + (lane >> 4) * 8 + j;
        n = nt * 16 + (lane & 15);
        t = k >> 1; q = k & 1; f = n >> 1; e = n & 1;
    }
    int ft = (f * t) & (T - 1);
    float sv, cv;
    sincosf((float)ft * 0.012271846303085129f, &sv, &cv);
    const float sc = 0.04419417382415922f;
    cv *= sc; sv *= sc;
    float val;
    if (!which) val = (e == 0) ? (q == 0 ? cv : -sv) : (q == 0 ?  sv : cv);
    else        val = (e == 0) ? (q == 0 ? cv :  sv) : (q == 0 ? -sv : cv);
    f16* dst = (f16*)(ws + (which ? OFF_W2H : OFF_W1H));
    dst[id] = (f16)val;
}

__device__ __forceinline__ int zlin(int row, int fc) {   // row 0..63, fc 0..95
    return (((row >> 4) * 3 + (fc >> 5)) * 64 + ((fc >> 3) & 3) * 16 + (row & 15)) * 8 + (fc & 7);
}

// Fused layer kernel. mode 0: first (z=u_s, Z-GEMM only). mode 1: mid (full).
// mode 2: last (h-GEMM only, writes out). 256 thr = 4 waves x 16 rows; 64 rows/block.
__global__ __launch_bounds__(256) void F(const float* __restrict__ u, float* __restrict__ ws,
                                         const float* __restrict__ S1, const float* __restrict__ S2,
                                         float* __restrict__ out, int layer, int mode) {
    __shared__ f16 wbuf[2][12288];
    __shared__ f16 zfh[6144], zfl[6144];
    __shared__ float garr[NRI];
    __shared__ float lsum[NRI];

    const int tid = threadIdx.x;
    const int wv = tid >> 6;
    const int lane = tid & 63;
    const int quad = lane >> 4;
    const int l15 = lane & 15;
    const int m0 = blockIdx.x * 64;
    const int mrow = m0 + wv * 16;           // this wave's 16-row tile base

    float* __restrict__ Rbuf = ws + OFF_R;
    const float s5 = ws[OFF_SCALE];

    if (mode >= 1) {
        const float* sums_in = ws + OFF_SUMS + layer * NRI;
        float s1 = S1[0], s2 = S2[0];
        for (int i = tid; i < NRI; i += 256) {
            int t2 = (i >> 1) << 1;
            float sm = sums_in[t2] + sums_in[t2 + 1];
            float rm = sqrtf(sm * (1.0f / 16384.0f));
            garr[i] = 1.0f / (1.0f + expf(-s1 * (rm - s2)));
        }
    }
    for (int i = tid; i < NRI; i += 256) lsum[i] = 0.0f;
    if (mode == 0) {
        for (int i = tid; i < 6144; i += 256) {
            int row = i / 96, fc = i - row * 96;
            float z = s5 * u[(size_t)(m0 + row) * 96 + fc];
            f16 zh_ = (f16)z;
            int li = zlin(row, fc);
            zfh[li] = zh_;
            zfl[li] = (f16)(z - (float)zh_);
        }
    }
    __syncthreads();

    // ---------------- phase h: h = (g.R) x W2, M-split across waves ----------------
    if (mode >= 1) {
        const float4* w2 = (const float4*)(ws + OFF_W2H);      // 1536 float4 per chunk
        float4 pre[6];
#pragma unroll
        for (int s = 0; s < 6; s++) pre[s] = w2[s * 256 + tid];
        {
            float4* db = (float4*)(&wbuf[0][0]);
#pragma unroll
            for (int s = 0; s < 6; s++) db[s * 256 + tid] = pre[s];
        }
        __syncthreads();

        floatx4 acc[6];
#pragma unroll
        for (int nt = 0; nt < 6; nt++) acc[nt] = (floatx4){0.f, 0.f, 0.f, 0.f};
        const float* rrow = Rbuf + (size_t)(mrow + l15) * NRI;

        for (int ch = 0; ch < 8; ch++) {
            if (ch < 7) {
#pragma unroll
                for (int s = 0; s < 6; s++) pre[s] = w2[(ch + 1) * 1536 + s * 256 + tid];
            }
            const f16* wb = &wbuf[ch & 1][0];
#pragma unroll
            for (int kc = 0; kc < 4; kc++) {
                int kb = ch * 128 + kc * 32 + quad * 8;
                float4 a0 = *(const float4*)(rrow + kb);
                float4 a1 = *(const float4*)(rrow + kb + 4);
                float4 g0 = *(const float4*)(garr + kb);
                float4 g1 = *(const float4*)(garr + kb + 4);
                float hv[8] = {a0.x * g0.x, a0.y * g0.y, a0.z * g0.z, a0.w * g0.w,
                               a1.x * g1.x, a1.y * g1.y, a1.z * g1.z, a1.w * g1.w};
                half8 Ah, Al;
#pragma unroll
                for (int j = 0; j < 8; j++) {
                    f16 h = (f16)hv[j];
                    Ah[j] = h;
                    Al[j] = (f16)(hv[j] - (float)h);
                }
#pragma unroll
                for (int nt = 0; nt < 6; nt++) {
                    half8 Bv = *(const half8*)(wb + ((kc * 6 + nt) * 64 + lane) * 8);
                    acc[nt] = __builtin_amdgcn_mfma_f32_16x16x32_f16(Ah, Bv, acc[nt], 0, 0, 0);
                    acc[nt] = __builtin_amdgcn_mfma_f32_16x16x32_f16(Al, Bv, acc[nt], 0, 0, 0);
                }
            }
            if (ch < 7) {
                float4* db = (float4*)(&wbuf[(ch + 1) & 1][0]);
#pragma unroll
                for (int s = 0; s < 6; s++) db[s * 256 + tid] = pre[s];
                __syncthreads();
            }
        }

        // epilogue: z = u_s - h (mode 1) or out = h * max/5 (mode 2)
        if (mode == 1) {
#pragma unroll
            for (int nt = 0; nt < 6; nt++) {
#pragma unroll
                for (int r = 0; r < 4; r++) {
                    int rowg = mrow + quad * 4 + r;
                    int fc = nt * 16 + l15;
                    float z = fmaf(s5, u[(size_t)rowg * 96 + fc], -acc[nt][r]);
                    f16 zh_ = (f16)z;
                    int li = zlin(rowg - m0, fc);
                    zfh[li] = zh_;
                    zfl[li] = (f16)(z - (float)zh_);
                }
            }
        } else {
            float is = ws[OFF_SCALE + 1];
#pragma unroll
            for (int nt = 0; nt < 6; nt++) {
#pragma unroll
                for (int r = 0; r < 4; r++) {
                    int rowg = mrow + quad * 4 + r;
                    int fc = nt * 16 + l15;
                    out[(size_t)rowg * 96 + fc] = acc[nt][r] * is;
                }
            }
        }
        __syncthreads();   // zfrag visible; wbuf free for phase Z
    }

    // ---------------- phase Z: C = z x W1 ; R' = g.R + C ; sums ----------------
    if (mode <= 1) {
        const float4* w1 = (const float4*)(ws + OFF_W1H);
        float4 pre[6];
#pragma unroll
        for (int s = 0; s < 6; s++) pre[s] = w1[s * 256 + tid];
        {
            float4* db = (float4*)(&wbuf[0][0]);
#pragma unroll
            for (int s = 0; s < 6; s++) db[s * 256 + tid] = pre[s];
        }
        __syncthreads();

        float* __restrict__ sums_out = ws + OFF_SUMS + (layer + 1) * NRI;

        for (int ch = 0; ch < 8; ch++) {
            if (ch < 7) {
#pragma unroll
                for (int s = 0; s < 6; s++) pre[s] = w1[(ch + 1) * 1536 + s * 256 + tid];
            }
            const f16* wb = &wbuf[ch & 1][0];
            floatx4 acc2[8];
#pragma unroll
            for (int nt = 0; nt < 8; nt++) acc2[nt] = (floatx4){0.f, 0.f, 0.f, 0.f};
#pragma unroll
            for (int kc = 0; kc < 3; kc++) {
                half8 Ah = *(const half8*)(zfh + ((wv * 3 + kc) * 64 + lane) * 8);
                half8 Al = *(const half8*)(zfl + ((wv * 3 + kc) * 64 + lane) * 8);
#pragma unroll
                for (int nt = 0; nt < 8; nt++) {
                    half8 Bv = *(const half8*)(wb + ((nt * 3 + kc) * 64 + lane) * 8);
                    acc2[nt] = __builtin_amdgcn_mfma_f32_16x16x32_f16(Ah, Bv, acc2[nt], 0, 0, 0);
                    acc2[nt] = __builtin_amdgcn_mfma_f32_16x16x32_f16(Al, Bv, acc2[nt], 0, 0, 0);
                }
            }
#pragma unroll
            for (int nt = 0; nt < 8; nt++) {
                int n = ch * 128 + nt * 16 + l15;
                float csum = 0.0f;
#pragma unroll
                for (int r = 0; r < 4; r++) {
                    size_t idx = (size_t)(mrow + quad * 4 + r) * NRI + n;
                    float Rv = acc2[nt][r];
                    if (mode == 1) Rv = fmaf(garr[n], Rbuf[idx], Rv);
                    Rbuf[idx] = Rv;
                    csum = fmaf(Rv, Rv, csum);
                }
                csum += __shfl_xor(csum, 16, 64);
                csum += __shfl_xor(csum, 32, 64);
                if (lane < 16) atomicAdd(&lsum[n], csum);
            }
            if (ch < 7) {
                float4* db = (float4*)(&wbuf[(ch + 1) & 1][0]);
#pragma unroll
                for (int s = 0; s < 6; s++) db[s * 256 + tid] = pre[s];
            }
            __syncthreads();
        }
        for (int i = tid; i < NRI; i += 256) atomicAdd(&sums_out[i], lsum[i]);
    }
}

extern "C" void kernel_launch(void* const* d_in, const int* in_sizes, int n_in,
                              void* d_out, int out_size, void* d_ws, size_t ws_size,
                              hipStream_t stream) {
    const float* u  = (const float*)d_in[0];
    const float* S1 = (const float*)d_in[1];
    const float* S2 = (const float*)d_in[2];
    float* out = (float*)d_out;
    float* ws  = (float*)d_ws;
    int n = in_sizes[0];

    kmax<<<256, 256, 0, stream>>>(u, ws + OFF_PMAX, n);
    kinit<<<1, 256, 0, stream>>>(ws);
    kwf<<<768, 256, 0, stream>>>(ws);

    F<<<256, 256, 0, stream>>>(u, ws, S1, S2, out, -1, 0);
    for (int l = 0; l < LAYERS - 1; l++)
        F<<<256, 256, 0, stream>>>(u, ws, S1, S2, out, l, 1);
    F<<<256, 256, 0, stream>>>(u, ws, S1, S2, out, LAYERS - 1, 2);
}